// Round 7
// baseline (1088.986 us; speedup 1.0000x reference)
//
#include <hip/hip_runtime.h>
#include <hip/hip_bf16.h>
#include <math.h>

#define B_   64
#define T_   512
#define F_   256
#define ENC_ 256
#define P_   128
#define H_   256
#define K_   12
#define INV_TEMP 10.0f

typedef unsigned short u16;
typedef _Float16 half2v __attribute__((ext_vector_type(2)));
union U2H { unsigned int u; half2v h; };
typedef __attribute__((ext_vector_type(8))) short bf16x8;   // 8 bf16 = 4 VGPRs
typedef __attribute__((ext_vector_type(4))) float f32x4;    // MFMA C/D
typedef _Float16 f16x8 __attribute__((ext_vector_type(8))); // 8 f16 = 4 VGPRs
union BF8 { bf16x8 v; u16 e[8]; };

// ---------------- helpers ----------------------------------------------------
__device__ __forceinline__ float rcpf(float x) {
#if __has_builtin(__builtin_amdgcn_rcpf)
    return __builtin_amdgcn_rcpf(x);
#else
    return 1.f / x;
#endif
}
__device__ __forceinline__ u16 f2bf(float f) {   // RNE
    unsigned int u = __float_as_uint(f);
    unsigned int r = (u + 0x7fffu + ((u >> 16) & 1u)) >> 16;
    return (u16)r;
}
__device__ __forceinline__ float bf2f(u16 v) {
    return __uint_as_float(((unsigned int)v) << 16);
}
__device__ __forceinline__ float bflo(unsigned int u) { return __uint_as_float(u << 16); }
__device__ __forceinline__ float bfhi(unsigned int u) { return __uint_as_float(u & 0xffff0000u); }
__device__ __forceinline__ float wave_sum(float v) {
    #pragma unroll
    for (int o = 32; o > 0; o >>= 1) v += __shfl_down(v, o, 64);
    return v;
}

// ---------------- merged setup: weight conversions + fold + accum zero -------
// blocks 0..191: Wh -> Wht f16 (transposed, [768][256] = MFMA B^T layout);
// 192..287: Wi -> Wit bf16 (transposed); 288..671: Wp -> Wpt bf16 (transposed);
// 672..800: fold (Wct, bc, accum=0)
__global__ __launch_bounds__(256) void setup_conv(const float* __restrict__ Wh,
                                                  _Float16* __restrict__ Wht,
                                                  const float* __restrict__ Wi,
                                                  u16* __restrict__ Wit,
                                                  const float* __restrict__ Wp,
                                                  u16* __restrict__ Wpt,
                                                  const float* __restrict__ We,
                                                  const float* __restrict__ be,
                                                  const float* __restrict__ Wpj,
                                                  const float* __restrict__ bpj,
                                                  u16* __restrict__ Wct,
                                                  float* __restrict__ bc,
                                                  float* __restrict__ accum) {
    int bid = blockIdx.x;
    if (bid < 192) {
        // Wht[g][k] = (f16)Wh[k][g]  (768x256 out of 256x768 in; 24x8 32x32 tiles)
        __shared__ float tile0[32][33];
        int g0 = (bid % 24) * 32, k0 = (bid / 24) * 32;
        int tx = threadIdx.x & 31, ty = threadIdx.x >> 5;
        #pragma unroll
        for (int i = 0; i < 32; i += 8)
            tile0[ty + i][tx] = Wh[(size_t)(k0 + ty + i) * 768 + g0 + tx];
        __syncthreads();
        #pragma unroll
        for (int i = 0; i < 32; i += 8)
            Wht[(size_t)(g0 + ty + i) * 256 + k0 + tx] = (_Float16)tile0[tx][ty + i];
    } else if (bid < 288) {
        __shared__ float tile[32][33];
        int b2 = bid - 192;                       // 0..95
        int n0 = (b2 % 24) * 32, k0 = (b2 / 24) * 32;
        int tx = threadIdx.x & 31, ty = threadIdx.x >> 5;
        #pragma unroll
        for (int i = 0; i < 32; i += 8)
            tile[ty + i][tx] = Wi[(size_t)(k0 + ty + i) * 768 + n0 + tx];
        __syncthreads();
        #pragma unroll
        for (int i = 0; i < 32; i += 8)
            Wit[(size_t)(n0 + ty + i) * 128 + k0 + tx] = f2bf(tile[tx][ty + i]);
    } else if (bid < 672) {
        __shared__ float tile2[32][33];
        int b3 = bid - 288;                       // 0..383
        int kq = b3 / 32, rem = b3 % 32;
        int h0 = (rem % 8) * 32, p0 = (rem / 8) * 32;
        int tx = threadIdx.x & 31, ty = threadIdx.x >> 5;
        #pragma unroll
        for (int i = 0; i < 32; i += 8)
            tile2[ty + i][tx] = Wp[(size_t)kq * H_ * P_ + (size_t)(h0 + ty + i) * P_ + p0 + tx];
        __syncthreads();
        #pragma unroll
        for (int i = 0; i < 32; i += 8)
            Wpt[(size_t)kq * P_ * H_ + (size_t)(p0 + ty + i) * H_ + h0 + tx] = f2bf(tile2[tx][ty + i]);
    } else {
        // fold: f = 2*(bid-672) + (tid>>7); p = tid&127
        int f = (bid - 672) * 2 + (threadIdx.x >> 7);
        int p = threadIdx.x & 127;
        if (f < F_) {
            float a = 0.f;
            for (int e = 0; e < ENC_; e++) a = fmaf(We[f * ENC_ + e], Wpj[e * P_ + p], a);
            Wct[(size_t)p * F_ + f] = f2bf(a);
        } else if (f == F_) {
            float a = bpj[p];
            for (int e = 0; e < ENC_; e++) a = fmaf(be[e], Wpj[e * P_ + p], a);
            bc[p] = a;
        } else {
            #pragma unroll
            for (int i = 0; i < 8; i++) accum[p * 8 + i] = 0.f;
        }
    }
}

// ---------------- MFMA GEMM, A = fp32 (converted in-register) ----------------
__global__ __launch_bounds__(256) void gemm_mfma_f32a(const float* __restrict__ A,
                                                      const u16* __restrict__ Bt,
                                                      const float* __restrict__ bias,
                                                      u16* __restrict__ Ch,
                                                      int N, int K) {
    int tid  = threadIdx.x;
    int w    = tid >> 6;
    int lane = tid & 63;
    int col  = lane & 15;
    int quad = lane >> 4;
    int bm = blockIdx.y * 64, bn = blockIdx.x * 128;

    f32x4 acc[8] = {};
    const float* arow = A + (size_t)(bm + w * 16 + col) * K;
    #pragma unroll
    for (int k0 = 0; k0 < K; k0 += 32) {
        float4 v0 = *(const float4*)(arow + k0 + quad * 8);
        float4 v1 = *(const float4*)(arow + k0 + quad * 8 + 4);
        BF8 af;
        af.e[0] = f2bf(v0.x); af.e[1] = f2bf(v0.y); af.e[2] = f2bf(v0.z); af.e[3] = f2bf(v0.w);
        af.e[4] = f2bf(v1.x); af.e[5] = f2bf(v1.y); af.e[6] = f2bf(v1.z); af.e[7] = f2bf(v1.w);
        #pragma unroll
        for (int nt = 0; nt < 8; nt++) {
            bf16x8 bf = *(const bf16x8*)(Bt + (size_t)(bn + nt * 16 + col) * K + k0 + quad * 8);
            acc[nt] = __builtin_amdgcn_mfma_f32_16x16x32_bf16(af.v, bf, acc[nt], 0, 0, 0);
        }
    }
    #pragma unroll
    for (int nt = 0; nt < 8; nt++) {
        int gn = bn + nt * 16 + col;
        float bv = bias[gn];
        #pragma unroll
        for (int r = 0; r < 4; r++) {
            int gm = bm + w * 16 + quad * 4 + r;
            Ch[(size_t)gm * N + gn] = f2bf(acc[nt][r] + bv);
        }
    }
}

// ---------------- MFMA GEMM, A = bf16, C = bf16 ------------------------------
__global__ __launch_bounds__(256) void gemm_mfma(const u16* __restrict__ A,
                                                 const u16* __restrict__ Bt,
                                                 const float* __restrict__ bias,
                                                 u16* __restrict__ Ch,
                                                 int N, int K) {
    int tid  = threadIdx.x;
    int w    = tid >> 6;
    int lane = tid & 63;
    int col  = lane & 15;
    int quad = lane >> 4;
    int bm = blockIdx.y * 64, bn = blockIdx.x * 128;

    f32x4 acc[8] = {};
    const u16* arow = A + (size_t)(bm + w * 16 + col) * K;
    #pragma unroll
    for (int k0 = 0; k0 < K; k0 += 32) {
        bf16x8 af = *(const bf16x8*)(arow + k0 + quad * 8);
        #pragma unroll
        for (int nt = 0; nt < 8; nt++) {
            bf16x8 bf = *(const bf16x8*)(Bt + (size_t)(bn + nt * 16 + col) * K + k0 + quad * 8);
            acc[nt] = __builtin_amdgcn_mfma_f32_16x16x32_bf16(af, bf, acc[nt], 0, 0, 0);
        }
    }
    #pragma unroll
    for (int nt = 0; nt < 8; nt++) {
        int gn = bn + nt * 16 + col;
        float bv = bias[gn];
        #pragma unroll
        for (int r = 0; r < 4; r++) {
            int gm = bm + w * 16 + quad * 4 + r;
            Ch[(size_t)gm * N + gn] = f2bf(acc[nt][r] + bv);
        }
    }
}

// ---------------- GRU scan (blocks 0..63) + zsum (blocks 64..127) ------------
// r2-proven structure (measured 537us): MFMA recurrence, M=16 replicated rows,
// 1 batch/block; per-lane gi prefetch; raw s_barrier (no vmcnt drain).
#define GRUB_ 64

__global__ __attribute__((amdgpu_flat_work_group_size(512, 512)))
void gru_zsum_kernel(const u16* __restrict__ gi,
                     const _Float16* __restrict__ Wht,
                     const float* __restrict__ bhn,
                     u16* __restrict__ ch,
                     const u16* __restrict__ zh,
                     float* __restrict__ zsum) {
    __shared__ __align__(16) char smem[8704];
    int tid = threadIdx.x;          // 0..511

    if (blockIdx.x >= GRUB_) {
        // ---- zsum[b][p] = sum_{t=1..T-1} z[b][t][p], 16-way t-split ---------
        float (*part)[128] = (float (*)[128])smem;   // 8192 B
        int b   = blockIdx.x - GRUB_;
        int pg  = tid & 31;
        int g   = tid >> 5;
        const u16* zb = zh + (size_t)b * T_ * P_;
        float s0 = 0.f, s1 = 0.f, s2 = 0.f, s3 = 0.f;
        for (int t = 1 + g; t < T_; t += 16) {
            uint2 v = *(const uint2*)(zb + (size_t)t * P_ + pg * 4);
            s0 += bflo(v.x); s1 += bfhi(v.x);
            s2 += bflo(v.y); s3 += bfhi(v.y);
        }
        part[g][pg * 4 + 0] = s0; part[g][pg * 4 + 1] = s1;
        part[g][pg * 4 + 2] = s2; part[g][pg * 4 + 3] = s3;
        __syncthreads();
        if (tid < 128) {
            float s = 0.f;
            #pragma unroll
            for (int g2 = 0; g2 < 16; g2++) s += part[g2][tid];
            zsum[(size_t)b * P_ + tid] = s;
        }
        return;
    }

    // ---- GRU, 1 batch/block -------------------------------------------------
    _Float16* hbase = (_Float16*)smem;           // [2][264] f16 double buffer

    int lane = tid & 63, w = tid >> 6;
    int col  = lane & 15, quad = lane >> 4;
    int b    = blockIdx.x;
    int jj0  = w * 32 + col;                     // n2=0 gate-col; n2=1 adds 16

    // B fragments: wf[gate][n2][k0] = Wht[gcol][k0*32 + quad*8 .. +7]
    f16x8 wf[3][2][8];
    #pragma unroll
    for (int g = 0; g < 3; g++)
        #pragma unroll
        for (int n2 = 0; n2 < 2; n2++) {
            const _Float16* src = Wht + (size_t)(g * 256 + jj0 + n2 * 16) * 256 + quad * 8;
            #pragma unroll
            for (int k0 = 0; k0 < 8; k0++)
                wf[g][n2][k0] = *(const f16x8*)(src + k0 * 32);
        }
    // pin: asm is the value source -> no in-loop reload/remat
    #pragma unroll
    for (int g = 0; g < 3; g++)
        #pragma unroll
        for (int n2 = 0; n2 < 2; n2++)
            #pragma unroll
            for (int k0 = 0; k0 < 8; k0++)
                asm volatile("" : "+v"(wf[g][n2][k0]));

    for (int i = tid; i < 528; i += 512) hbase[i] = (_Float16)0.f;

    const u16* gb = gi + (size_t)b * T_ * 768;
    u16* cb       = ch + (size_t)b * T_ * 256;
    float bh0 = bhn[jj0], bh1 = bhn[jj0 + 16];
    float hold0 = 0.f, hold1 = 0.f;
    unsigned int pf[6];

    {   // preload t=0 gate inputs
        pf[0] = gb[jj0];        pf[1] = gb[jj0 + 16];
        pf[2] = gb[256 + jj0];  pf[3] = gb[256 + jj0 + 16];
        pf[4] = gb[512 + jj0];  pf[5] = gb[512 + jj0 + 16];
    }
    __syncthreads();     // h zeros visible (one-time full drain is fine)

    auto body = [&](int t, int c) {
        int n = c ^ 1;
        const _Float16* HC = hbase + c * 264;
        _Float16*       HN = hbase + n * 264;
        // gh = h(t-1) @ Wh : 48 MFMA (3 gates x 2 col-tiles x 8 K-tiles)
        f32x4 aR0 = {}, aR1 = {}, aZ0 = {}, aZ1 = {}, aN0 = {}, aN1 = {};
        #pragma unroll
        for (int k0 = 0; k0 < 8; k0++) {
            f16x8 af = *(const f16x8*)(HC + k0 * 32 + quad * 8);   // broadcast read
            aR0 = __builtin_amdgcn_mfma_f32_16x16x32_f16(af, wf[0][0][k0], aR0, 0, 0, 0);
            aR1 = __builtin_amdgcn_mfma_f32_16x16x32_f16(af, wf[0][1][k0], aR1, 0, 0, 0);
            aZ0 = __builtin_amdgcn_mfma_f32_16x16x32_f16(af, wf[1][0][k0], aZ0, 0, 0, 0);
            aZ1 = __builtin_amdgcn_mfma_f32_16x16x32_f16(af, wf[1][1][k0], aZ1, 0, 0, 0);
            aN0 = __builtin_amdgcn_mfma_f32_16x16x32_f16(af, wf[2][0][k0], aN0, 0, 0, 0);
            aN1 = __builtin_amdgcn_mfma_f32_16x16x32_f16(af, wf[2][1][k0], aN1, 0, 0, 0);
        }
        // all 16 C-rows identical (replicated A) -> element [0] is THE value
        float rg0 = rcpf(1.f + __expf(-(bf2f((u16)pf[0]) + aR0[0])));
        float rg1 = rcpf(1.f + __expf(-(bf2f((u16)pf[1]) + aR1[0])));
        float zg0 = rcpf(1.f + __expf(-(bf2f((u16)pf[2]) + aZ0[0])));
        float zg1 = rcpf(1.f + __expf(-(bf2f((u16)pf[3]) + aZ1[0])));
        float xn0 = bf2f((u16)pf[4]) + rg0 * (aN0[0] + bh0);
        float xn1 = bf2f((u16)pf[5]) + rg1 * (aN1[0] + bh1);
        float nn0 = fmaf(2.f, rcpf(1.f + __expf(-2.f * xn0)), -1.f);
        float nn1 = fmaf(2.f, rcpf(1.f + __expf(-2.f * xn1)), -1.f);
        hold0 = (1.f - zg0) * nn0 + zg0 * hold0;
        hold1 = (1.f - zg1) * nn1 + zg1 * hold1;
        if (quad == 0) {                 // LDS h for next step
            HN[jj0]      = (_Float16)hold0;
            HN[jj0 + 16] = (_Float16)hold1;
        } else if (quad == 1) {          // global ch (redundant copies identical)
            u16* cr = cb + (size_t)t * 256;
            cr[jj0]      = f2bf(hold0);
            cr[jj0 + 16] = f2bf(hold1);
        }
        // prefetch gi(t+1) AFTER pf consumed (counted vmcnt, never drained)
        if (t + 1 < T_) {
            const u16* gr = gb + (size_t)(t + 1) * 768;
            pf[0] = gr[jj0];        pf[1] = gr[jj0 + 16];
            pf[2] = gr[256 + jj0];  pf[3] = gr[256 + jj0 + 16];
            pf[4] = gr[512 + jj0];  pf[5] = gr[512 + jj0 + 16];
        }
        asm volatile("s_waitcnt lgkmcnt(0)" ::: "memory");
        __builtin_amdgcn_s_barrier();
        asm volatile("" ::: "memory");
    };

    #pragma unroll 1
    for (int t = 0; t < T_; t += 2) {
        body(t,     0);
        body(t + 1, 1);
    }
}

// ---------------- fused loss, MFMA; 64-row tiles; 3 k-values per block -------
// r6 post-mortem: Pst[3][128] = 123 KB LDS -> 1 block/CU, softmax exposed.
// Fix: 64-row tiles, 256 threads, LDS 71 KB -> 2 blocks/CU; two independent
// blocks interleave (block A softmax overlaps block B MFMA, m114). Same total
// MFMA (work/row invariant). t0 is blockIdx.x (fastest) -> 8 consecutive
// blocks share one zh[b] stream (L2-resident). Zt reg-prefetched (T14).
__global__ __launch_bounds__(256) void loss_fused(const u16* __restrict__ ch,
                                                  const u16* __restrict__ Wpt,
                                                  const float* __restrict__ bp,
                                                  const u16* __restrict__ zh,
                                                  const float* __restrict__ zsum,
                                                  float* __restrict__ accum) {
    __shared__ u16 Pst[3][64][136];      // 52224 B
    __shared__ u16 Zt[64][136];          // 17408 B
    __shared__ float sS[3][128];         //  1536 B
    __shared__ float red[4];
    int kz    = blockIdx.z;              // 0..3
    int kbase = 1 + kz * 3;              // k = kbase + j, j = 0..2
    int b  = blockIdx.y;
    int t0 = blockIdx.x * 64;
    int tid  = threadIdx.x;              // 0..255
    int w    = tid >> 6;                 // 0..3
    int lane = tid & 63;
    int col  = lane & 15;
    int quad = lane >> 4;
    const u16* zb = zh + (size_t)b * T_ * P_;

    // issue first Zt tile loads ASAP (latency hidden under phase 1)
    int rr  = tid >> 4;                  // 0..15
    int off = (tid & 15) * 8;
    uint4 rA = *(const uint4*)(zb + (size_t)(kbase + rr)      * P_ + off);
    uint4 rB = *(const uint4*)(zb + (size_t)(kbase + rr + 16) * P_ + off);
    uint4 rC = *(const uint4*)(zb + (size_t)(kbase + rr + 32) * P_ + off);
    uint4 rD = *(const uint4*)(zb + (size_t)(kbase + rr + 48) * P_ + off);

    // S_bk for the 3 k's (incremental)
    if (tid < 128) {
        float s = zsum[(size_t)b * P_ + tid];
        for (int t = 1; t < kbase; t++) s -= bf2f(zb[(size_t)t * P_ + tid]);
        sS[0][tid] = s;
        s -= bf2f(zb[(size_t)kbase * P_ + tid]);       sS[1][tid] = s;
        s -= bf2f(zb[(size_t)(kbase + 1) * P_ + tid]); sS[2][tid] = s;
    }

    // ---- phase 1: Pst[j] = bf16(ch-tile @ Wp[kbase+j] + bp), af hoisted -----
    {
        f32x4 acc[3][8] = {};
        const u16* arow = ch + ((size_t)b * T_ + t0 + w * 16 + col) * H_;
        const u16* wk   = Wpt + (size_t)(kbase - 1) * P_ * H_;
        #pragma unroll
        for (int k0 = 0; k0 < 8; k0++) {
            bf16x8 af = *(const bf16x8*)(arow + k0 * 32 + quad * 8);
            #pragma unroll
            for (int j = 0; j < 3; j++)
                #pragma unroll
                for (int nt = 0; nt < 8; nt++) {
                    bf16x8 bf = *(const bf16x8*)(wk + (size_t)j * P_ * H_
                                 + (size_t)(nt * 16 + col) * H_ + k0 * 32 + quad * 8);
                    acc[j][nt] = __builtin_amdgcn_mfma_f32_16x16x32_bf16(af, bf, acc[j][nt], 0, 0, 0);
                }
        }
        #pragma unroll
        for (int j = 0; j < 3; j++)
            #pragma unroll
            for (int nt = 0; nt < 8; nt++) {
                float bias = bp[(size_t)(kbase - 1 + j) * P_ + nt * 16 + col];
                #pragma unroll
                for (int r = 0; r < 4; r++)
                    Pst[j][w * 16 + quad * 4 + r][nt * 16 + col] = f2bf(acc[j][nt][r] + bias);
            }
    }
    __syncthreads();

    // ---- phase 2: flash LSE x3 over ONE shared Zt stream --------------------
    float mloc[3][4], sloc[3][4];
    #pragma unroll
    for (int j = 0; j < 3; j++)
        #pragma unroll
        for (int r = 0; r < 4; r++) { mloc[j][r] = -INFINITY; sloc[j][r] = 0.f; }

    int TkMax = T_ - kbase;              // j=0 has the longest range
    for (int ct = 0; ct < TkMax; ct += 64) {
        __syncthreads();                 // Zt free (prev tile's MFMAs done)
        *(uint4*)&Zt[rr][off]      = rA;
        *(uint4*)&Zt[rr + 16][off] = rB;
        *(uint4*)&Zt[rr + 32][off] = rC;
        *(uint4*)&Zt[rr + 48][off] = rD;
        __syncthreads();
        if (ct + 64 < TkMax) {           // prefetch next tile (over-read masked)
            int tc = kbase + ct + 64;
            rA = *(const uint4*)(zb + (size_t)(tc + rr)      * P_ + off);
            rB = *(const uint4*)(zb + (size_t)(tc + rr + 16) * P_ + off);
            rC = *(const uint4*)(zb + (size_t)(tc + rr + 32) * P_ + off);
            rD = *(const uint4*)(zb + (size_t)(tc + rr + 48) * P_ + off);
        }
        f32x4 acc[3][4] = {};
        #pragma unroll
        for (int k0 = 0; k0 < 4; k0++) {
            bf16x8 pa0 = *(const bf16x8*)(&Pst[0][w * 16 + col][k0 * 32 + quad * 8]);
            bf16x8 pa1 = *(const bf16x8*)(&Pst[1][w * 16 + col][k0 * 32 + quad * 8]);
            bf16x8 pa2 = *(const bf16x8*)(&Pst[2][w * 16 + col][k0 * 32 + quad * 8]);
            #pragma unroll
            for (int nt = 0; nt < 4; nt++) {
                bf16x8 bf = *(const bf16x8*)(&Zt[nt * 16 + col][k0 * 32 + quad * 8]);
                acc[0][nt] = __builtin_amdgcn_mfma_f32_16x16x32_bf16(pa0, bf, acc[0][nt], 0, 0, 0);
                acc[1][nt] = __builtin_amdgcn_mfma_f32_16x16x32_bf16(pa1, bf, acc[1][nt], 0, 0, 0);
                acc[2][nt] = __builtin_amdgcn_mfma_f32_16x16x32_bf16(pa2, bf, acc[2][nt], 0, 0, 0);
            }
        }
        #pragma unroll
        for (int j = 0; j < 3; j++) {
            #pragma unroll
            for (int r = 0; r < 4; r++) {
                float l[4];
                float tmax = -INFINITY;
                #pragma unroll
                for (int nt = 0; nt < 4; nt++) {
                    int cc = ct + nt * 16 + col;          // staged-buffer column
                    bool v = (cc >= j) && (kbase + cc < T_);
                    l[nt] = v ? acc[j][nt][r] * INV_TEMP : -INFINITY;
                    tmax = fmaxf(tmax, l[nt]);
                }
                float mnew = fmaxf(mloc[j][r], tmax);
                float e = __expf(l[0] - mnew) + __expf(l[1] - mnew)
                        + __expf(l[2] - mnew) + __expf(l[3] - mnew);
                sloc[j][r] = sloc[j][r] * __expf(mloc[j][r] - mnew) + e;
                mloc[j][r] = mnew;
            }
        }
    }
    // merge LSE across the 16-lane col groups
    #pragma unroll
    for (int j = 0; j < 3; j++)
        #pragma unroll
        for (int r = 0; r < 4; r++) {
            #pragma unroll
            for (int o = 1; o < 16; o <<= 1) {
                float mo = __shfl_xor(mloc[j][r], o, 64);
                float so = __shfl_xor(sloc[j][r], o, 64);
                float mn = fmaxf(mloc[j][r], mo);
                sloc[j][r] = sloc[j][r] * __expf(mloc[j][r] - mn) + so * __expf(mo - mn);
                mloc[j][r] = mn;
            }
        }
    float bs = 0.f;
    #pragma unroll
    for (int j = 0; j < 3; j++) {
        int Tkj = T_ - (kbase + j);
        float tkinv = INV_TEMP / (float)Tkj;
        float scale = 1.0f / ((float)K_ * (float)B_ * (float)Tkj);
        #pragma unroll
        for (int r = 0; r < 4; r++) {
            int row = w * 16 + quad * 4 + r;
            BF8 pv;
            pv.v = *(const bf16x8*)(&Pst[j][row][col * 8]);
            float d = 0.f;
            #pragma unroll
            for (int m = 0; m < 8; m++) d = fmaf(bf2f(pv.e[m]), sS[j][col * 8 + m], d);
            #pragma unroll
            for (int o = 1; o < 16; o <<= 1) d += __shfl_xor(d, o, 64);
            int gr = t0 + row;
            if (gr < Tkj) bs += (mloc[j][r] + __logf(sloc[j][r]) - d * tkinv) * scale;
        }
    }
    if (col != 0) bs = 0.f;
    bs = wave_sum(bs);
    if (lane == 0) red[w] = bs;
    __syncthreads();
    if (tid == 0) {
        float tot = red[0] + red[1] + red[2] + red[3];
        atomicAdd(&accum[(blockIdx.x * 809 + b * 67 + blockIdx.z * 131) & 1023], tot);
    }
}

__global__ void finalize(const float* __restrict__ accum, float* __restrict__ out) {
    int tid = threadIdx.x;
    __shared__ float red[4];
    float v = 0.f;
    for (int i = tid; i < 1024; i += 256) v += accum[i];
    float sres = wave_sum(v);
    if ((tid & 63) == 0) red[tid >> 6] = sres;
    __syncthreads();
    if (tid == 0) out[0] = red[0] + red[1] + red[2] + red[3];
}

// ---------------- launch -----------------------------------------------------
extern "C" void kernel_launch(void* const* d_in, const int* in_sizes, int n_in,
                              void* d_out, int out_size, void* d_ws, size_t ws_size,
                              hipStream_t stream) {
    const float* x      = (const float*)d_in[0];
    const float* W_enc  = (const float*)d_in[1];
    const float* b_enc  = (const float*)d_in[2];
    const float* W_proj = (const float*)d_in[3];
    const float* b_proj = (const float*)d_in[4];
    const float* Wi     = (const float*)d_in[5];
    const float* bi     = (const float*)d_in[6];
    const float* Wh     = (const float*)d_in[7];
    const float* bhn    = (const float*)d_in[8];
    const float* Wp     = (const float*)d_in[9];
    const float* bp     = (const float*)d_in[10];
    float* out = (float*)d_out;

    // layout (float offsets)
    float* ws    = (float*)d_ws;
    float* bc    = ws;                          // 128
    float* accum = bc + 128;                    // 1024 -> end 1152
    _Float16* Wht = (_Float16*)(ws + 1152);     // 196608 f16 = 98304 fl -> end 99456
    u16* Wct     = (u16*)(ws + 99456);          // 16384 fl -> end 115840
    u16* Wit     = (u16*)(ws + 115840);         // 49152 fl -> end 164992
    u16* Wpt     = (u16*)(ws + 164992);         // 196608 fl -> end 361600
    u16* zh      = (u16*)(ws + 361600);         // 2097152 fl -> end 2458752
    float* zsum  = ws + 2458752;                // 8192 fl (doubles as zh over-read slack) -> end 2466944
    u16* gi      = (u16*)(ws + 2466944);        // 12582912 fl -> end 15049856
    u16* ch      = (u16*)(ws + 15049856);       // 4194304 fl -> end 19244160 (~77 MB)

    const int MT = B_ * T_;                     // 32768

    // merged setup: all weight conversions + fold + accum zero (801 blocks)
    setup_conv<<<801, 256, 0, stream>>>(Wh, Wht, Wi, Wit, Wp, Wpt,
                                        W_enc, b_enc, W_proj, b_proj, Wct, bc, accum);
    // zh = bf16(x @ Wct^T + bc)   (M=32768, N=128, K=256; A converted in-reg)
    gemm_mfma_f32a<<<dim3(1, MT / 64), 256, 0, stream>>>(x, Wct, bc, zh, P_, F_);
    // gi = bf16(zh @ Wit^T + bi)  (M=32768, N=768, K=128)
    gemm_mfma<<<dim3(6, MT / 64), 256, 0, stream>>>(zh, Wit, bi, gi, 3 * H_, P_);
    // GRU scan (blocks 0..63) + zsum (64..127) — r2-proven structure
    gru_zsum_kernel<<<GRUB_ + B_, 512, 0, stream>>>(gi, Wht, bhn, ch, zh, zsum);
    // fused pred-GEMM + flash loss, 64-row tiles, 3 k/block, 2 blocks/CU
    loss_fused<<<dim3(8, B_, 4), 256, 0, stream>>>(ch, Wpt, bp, zh, zsum, accum);
    finalize<<<1, 256, 0, stream>>>(accum, out);
}

// Round 8
// 1043.891 us; speedup vs baseline: 1.0432x; 1.0432x over previous
//
#include <hip/hip_runtime.h>
#include <hip/hip_bf16.h>
#include <math.h>

#define B_   64
#define T_   512
#define F_   256
#define ENC_ 256
#define P_   128
#define H_   256
#define K_   12
#define INV_TEMP 10.0f

typedef unsigned short u16;
typedef _Float16 half2v __attribute__((ext_vector_type(2)));
union U2H { unsigned int u; half2v h; };
typedef __attribute__((ext_vector_type(8))) short bf16x8;   // 8 bf16 = 4 VGPRs
typedef __attribute__((ext_vector_type(4))) float f32x4;    // MFMA C/D
typedef _Float16 f16x8 __attribute__((ext_vector_type(8))); // 8 f16 = 4 VGPRs
union BF8 { bf16x8 v; u16 e[8]; };

// ---------------- helpers ----------------------------------------------------
__device__ __forceinline__ float rcpf(float x) {
#if __has_builtin(__builtin_amdgcn_rcpf)
    return __builtin_amdgcn_rcpf(x);
#else
    return 1.f / x;
#endif
}
__device__ __forceinline__ u16 f2bf(float f) {   // RNE
    unsigned int u = __float_as_uint(f);
    unsigned int r = (u + 0x7fffu + ((u >> 16) & 1u)) >> 16;
    return (u16)r;
}
__device__ __forceinline__ float bf2f(u16 v) {
    return __uint_as_float(((unsigned int)v) << 16);
}
__device__ __forceinline__ float bflo(unsigned int u) { return __uint_as_float(u << 16); }
__device__ __forceinline__ float bfhi(unsigned int u) { return __uint_as_float(u & 0xffff0000u); }
__device__ __forceinline__ float wave_sum(float v) {
    #pragma unroll
    for (int o = 32; o > 0; o >>= 1) v += __shfl_down(v, o, 64);
    return v;
}

// ---------------- merged setup: weight conversions + fold + accum zero -------
__global__ __launch_bounds__(256) void setup_conv(const float* __restrict__ Wh,
                                                  _Float16* __restrict__ Wht,
                                                  const float* __restrict__ Wi,
                                                  u16* __restrict__ Wit,
                                                  const float* __restrict__ Wp,
                                                  u16* __restrict__ Wpt,
                                                  const float* __restrict__ We,
                                                  const float* __restrict__ be,
                                                  const float* __restrict__ Wpj,
                                                  const float* __restrict__ bpj,
                                                  u16* __restrict__ Wct,
                                                  float* __restrict__ bc,
                                                  float* __restrict__ accum) {
    int bid = blockIdx.x;
    if (bid < 192) {
        // Wht[g][k] = (f16)Wh[k][g]  (768x256 out of 256x768 in; 24x8 32x32 tiles)
        __shared__ float tile0[32][33];
        int g0 = (bid % 24) * 32, k0 = (bid / 24) * 32;
        int tx = threadIdx.x & 31, ty = threadIdx.x >> 5;
        #pragma unroll
        for (int i = 0; i < 32; i += 8)
            tile0[ty + i][tx] = Wh[(size_t)(k0 + ty + i) * 768 + g0 + tx];
        __syncthreads();
        #pragma unroll
        for (int i = 0; i < 32; i += 8)
            Wht[(size_t)(g0 + ty + i) * 256 + k0 + tx] = (_Float16)tile0[tx][ty + i];
    } else if (bid < 288) {
        __shared__ float tile[32][33];
        int b2 = bid - 192;                       // 0..95
        int n0 = (b2 % 24) * 32, k0 = (b2 / 24) * 32;
        int tx = threadIdx.x & 31, ty = threadIdx.x >> 5;
        #pragma unroll
        for (int i = 0; i < 32; i += 8)
            tile[ty + i][tx] = Wi[(size_t)(k0 + ty + i) * 768 + n0 + tx];
        __syncthreads();
        #pragma unroll
        for (int i = 0; i < 32; i += 8)
            Wit[(size_t)(n0 + ty + i) * 128 + k0 + tx] = f2bf(tile[tx][ty + i]);
    } else if (bid < 672) {
        __shared__ float tile2[32][33];
        int b3 = bid - 288;                       // 0..383
        int kq = b3 / 32, rem = b3 % 32;
        int h0 = (rem % 8) * 32, p0 = (rem / 8) * 32;
        int tx = threadIdx.x & 31, ty = threadIdx.x >> 5;
        #pragma unroll
        for (int i = 0; i < 32; i += 8)
            tile2[ty + i][tx] = Wp[(size_t)kq * H_ * P_ + (size_t)(h0 + ty + i) * P_ + p0 + tx];
        __syncthreads();
        #pragma unroll
        for (int i = 0; i < 32; i += 8)
            Wpt[(size_t)kq * P_ * H_ + (size_t)(p0 + ty + i) * H_ + h0 + tx] = f2bf(tile2[tx][ty + i]);
    } else {
        // fold: f = 2*(bid-672) + (tid>>7); p = tid&127
        int f = (bid - 672) * 2 + (threadIdx.x >> 7);
        int p = threadIdx.x & 127;
        if (f < F_) {
            float a = 0.f;
            for (int e = 0; e < ENC_; e++) a = fmaf(We[f * ENC_ + e], Wpj[e * P_ + p], a);
            Wct[(size_t)p * F_ + f] = f2bf(a);
        } else if (f == F_) {
            float a = bpj[p];
            for (int e = 0; e < ENC_; e++) a = fmaf(be[e], Wpj[e * P_ + p], a);
            bc[p] = a;
        } else {
            #pragma unroll
            for (int i = 0; i < 8; i++) accum[p * 8 + i] = 0.f;
        }
    }
}

// ---------------- MFMA GEMM, A = fp32 (converted in-register) ----------------
__global__ __launch_bounds__(256) void gemm_mfma_f32a(const float* __restrict__ A,
                                                      const u16* __restrict__ Bt,
                                                      const float* __restrict__ bias,
                                                      u16* __restrict__ Ch,
                                                      int N, int K) {
    int tid  = threadIdx.x;
    int w    = tid >> 6;
    int lane = tid & 63;
    int col  = lane & 15;
    int quad = lane >> 4;
    int bm = blockIdx.y * 64, bn = blockIdx.x * 128;

    f32x4 acc[8] = {};
    const float* arow = A + (size_t)(bm + w * 16 + col) * K;
    #pragma unroll
    for (int k0 = 0; k0 < K; k0 += 32) {
        float4 v0 = *(const float4*)(arow + k0 + quad * 8);
        float4 v1 = *(const float4*)(arow + k0 + quad * 8 + 4);
        BF8 af;
        af.e[0] = f2bf(v0.x); af.e[1] = f2bf(v0.y); af.e[2] = f2bf(v0.z); af.e[3] = f2bf(v0.w);
        af.e[4] = f2bf(v1.x); af.e[5] = f2bf(v1.y); af.e[6] = f2bf(v1.z); af.e[7] = f2bf(v1.w);
        #pragma unroll
        for (int nt = 0; nt < 8; nt++) {
            bf16x8 bf = *(const bf16x8*)(Bt + (size_t)(bn + nt * 16 + col) * K + k0 + quad * 8);
            acc[nt] = __builtin_amdgcn_mfma_f32_16x16x32_bf16(af.v, bf, acc[nt], 0, 0, 0);
        }
    }
    #pragma unroll
    for (int nt = 0; nt < 8; nt++) {
        int gn = bn + nt * 16 + col;
        float bv = bias[gn];
        #pragma unroll
        for (int r = 0; r < 4; r++) {
            int gm = bm + w * 16 + quad * 4 + r;
            Ch[(size_t)gm * N + gn] = f2bf(acc[nt][r] + bv);
        }
    }
}

// ---------------- MFMA GEMM, A = bf16, C = bf16 ------------------------------
__global__ __launch_bounds__(256) void gemm_mfma(const u16* __restrict__ A,
                                                 const u16* __restrict__ Bt,
                                                 const float* __restrict__ bias,
                                                 u16* __restrict__ Ch,
                                                 int N, int K) {
    int tid  = threadIdx.x;
    int w    = tid >> 6;
    int lane = tid & 63;
    int col  = lane & 15;
    int quad = lane >> 4;
    int bm = blockIdx.y * 64, bn = blockIdx.x * 128;

    f32x4 acc[8] = {};
    const u16* arow = A + (size_t)(bm + w * 16 + col) * K;
    #pragma unroll
    for (int k0 = 0; k0 < K; k0 += 32) {
        bf16x8 af = *(const bf16x8*)(arow + k0 + quad * 8);
        #pragma unroll
        for (int nt = 0; nt < 8; nt++) {
            bf16x8 bf = *(const bf16x8*)(Bt + (size_t)(bn + nt * 16 + col) * K + k0 + quad * 8);
            acc[nt] = __builtin_amdgcn_mfma_f32_16x16x32_bf16(af, bf, acc[nt], 0, 0, 0);
        }
    }
    #pragma unroll
    for (int nt = 0; nt < 8; nt++) {
        int gn = bn + nt * 16 + col;
        float bv = bias[gn];
        #pragma unroll
        for (int r = 0; r < 4; r++) {
            int gm = bm + w * 16 + quad * 4 + r;
            Ch[(size_t)gm * N + gn] = f2bf(acc[nt][r] + bv);
        }
    }
}

// ---------------- GRU scan (blocks 0..63) + zsum (blocks 64..127) ------------
// r2-proven structure: MFMA recurrence, M=16 replicated rows, 1 batch/block.
#define GRUB_ 64

__global__ __attribute__((amdgpu_flat_work_group_size(512, 512)))
void gru_zsum_kernel(const u16* __restrict__ gi,
                     const _Float16* __restrict__ Wht,
                     const float* __restrict__ bhn,
                     u16* __restrict__ ch,
                     const u16* __restrict__ zh,
                     float* __restrict__ zsum) {
    __shared__ __align__(16) char smem[8704];
    int tid = threadIdx.x;          // 0..511

    if (blockIdx.x >= GRUB_) {
        // ---- zsum[b][p] = sum_{t=1..T-1} z[b][t][p], 16-way t-split ---------
        float (*part)[128] = (float (*)[128])smem;   // 8192 B
        int b   = blockIdx.x - GRUB_;
        int pg  = tid & 31;
        int g   = tid >> 5;
        const u16* zb = zh + (size_t)b * T_ * P_;
        float s0 = 0.f, s1 = 0.f, s2 = 0.f, s3 = 0.f;
        for (int t = 1 + g; t < T_; t += 16) {
            uint2 v = *(const uint2*)(zb + (size_t)t * P_ + pg * 4);
            s0 += bflo(v.x); s1 += bfhi(v.x);
            s2 += bflo(v.y); s3 += bfhi(v.y);
        }
        part[g][pg * 4 + 0] = s0; part[g][pg * 4 + 1] = s1;
        part[g][pg * 4 + 2] = s2; part[g][pg * 4 + 3] = s3;
        __syncthreads();
        if (tid < 128) {
            float s = 0.f;
            #pragma unroll
            for (int g2 = 0; g2 < 16; g2++) s += part[g2][tid];
            zsum[(size_t)b * P_ + tid] = s;
        }
        return;
    }

    // ---- GRU, 1 batch/block -------------------------------------------------
    _Float16* hbase = (_Float16*)smem;           // [2][264] f16 double buffer

    int lane = tid & 63, w = tid >> 6;
    int col  = lane & 15, quad = lane >> 4;
    int b    = blockIdx.x;
    int jj0  = w * 32 + col;                     // n2=0 gate-col; n2=1 adds 16

    f16x8 wf[3][2][8];
    #pragma unroll
    for (int g = 0; g < 3; g++)
        #pragma unroll
        for (int n2 = 0; n2 < 2; n2++) {
            const _Float16* src = Wht + (size_t)(g * 256 + jj0 + n2 * 16) * 256 + quad * 8;
            #pragma unroll
            for (int k0 = 0; k0 < 8; k0++)
                wf[g][n2][k0] = *(const f16x8*)(src + k0 * 32);
        }
    #pragma unroll
    for (int g = 0; g < 3; g++)
        #pragma unroll
        for (int n2 = 0; n2 < 2; n2++)
            #pragma unroll
            for (int k0 = 0; k0 < 8; k0++)
                asm volatile("" : "+v"(wf[g][n2][k0]));

    for (int i = tid; i < 528; i += 512) hbase[i] = (_Float16)0.f;

    const u16* gb = gi + (size_t)b * T_ * 768;
    u16* cb       = ch + (size_t)b * T_ * 256;
    float bh0 = bhn[jj0], bh1 = bhn[jj0 + 16];
    float hold0 = 0.f, hold1 = 0.f;
    unsigned int pf[6];

    {   // preload t=0 gate inputs
        pf[0] = gb[jj0];        pf[1] = gb[jj0 + 16];
        pf[2] = gb[256 + jj0];  pf[3] = gb[256 + jj0 + 16];
        pf[4] = gb[512 + jj0];  pf[5] = gb[512 + jj0 + 16];
    }
    __syncthreads();     // h zeros visible (one-time full drain is fine)

    auto body = [&](int t, int c) {
        int n = c ^ 1;
        const _Float16* HC = hbase + c * 264;
        _Float16*       HN = hbase + n * 264;
        f32x4 aR0 = {}, aR1 = {}, aZ0 = {}, aZ1 = {}, aN0 = {}, aN1 = {};
        #pragma unroll
        for (int k0 = 0; k0 < 8; k0++) {
            f16x8 af = *(const f16x8*)(HC + k0 * 32 + quad * 8);   // broadcast read
            aR0 = __builtin_amdgcn_mfma_f32_16x16x32_f16(af, wf[0][0][k0], aR0, 0, 0, 0);
            aR1 = __builtin_amdgcn_mfma_f32_16x16x32_f16(af, wf[0][1][k0], aR1, 0, 0, 0);
            aZ0 = __builtin_amdgcn_mfma_f32_16x16x32_f16(af, wf[1][0][k0], aZ0, 0, 0, 0);
            aZ1 = __builtin_amdgcn_mfma_f32_16x16x32_f16(af, wf[1][1][k0], aZ1, 0, 0, 0);
            aN0 = __builtin_amdgcn_mfma_f32_16x16x32_f16(af, wf[2][0][k0], aN0, 0, 0, 0);
            aN1 = __builtin_amdgcn_mfma_f32_16x16x32_f16(af, wf[2][1][k0], aN1, 0, 0, 0);
        }
        float rg0 = rcpf(1.f + __expf(-(bf2f((u16)pf[0]) + aR0[0])));
        float rg1 = rcpf(1.f + __expf(-(bf2f((u16)pf[1]) + aR1[0])));
        float zg0 = rcpf(1.f + __expf(-(bf2f((u16)pf[2]) + aZ0[0])));
        float zg1 = rcpf(1.f + __expf(-(bf2f((u16)pf[3]) + aZ1[0])));
        float xn0 = bf2f((u16)pf[4]) + rg0 * (aN0[0] + bh0);
        float xn1 = bf2f((u16)pf[5]) + rg1 * (aN1[0] + bh1);
        float nn0 = fmaf(2.f, rcpf(1.f + __expf(-2.f * xn0)), -1.f);
        float nn1 = fmaf(2.f, rcpf(1.f + __expf(-2.f * xn1)), -1.f);
        hold0 = (1.f - zg0) * nn0 + zg0 * hold0;
        hold1 = (1.f - zg1) * nn1 + zg1 * hold1;
        if (quad == 0) {                 // LDS h for next step
            HN[jj0]      = (_Float16)hold0;
            HN[jj0 + 16] = (_Float16)hold1;
        } else if (quad == 1) {          // global ch (redundant copies identical)
            u16* cr = cb + (size_t)t * 256;
            cr[jj0]      = f2bf(hold0);
            cr[jj0 + 16] = f2bf(hold1);
        }
        if (t + 1 < T_) {
            const u16* gr = gb + (size_t)(t + 1) * 768;
            pf[0] = gr[jj0];        pf[1] = gr[jj0 + 16];
            pf[2] = gr[256 + jj0];  pf[3] = gr[256 + jj0 + 16];
            pf[4] = gr[512 + jj0];  pf[5] = gr[512 + jj0 + 16];
        }
        asm volatile("s_waitcnt lgkmcnt(0)" ::: "memory");
        __builtin_amdgcn_s_barrier();
        asm volatile("" ::: "memory");
    };

    #pragma unroll 1
    for (int t = 0; t < T_; t += 2) {
        body(t,     0);
        body(t + 1, 1);
    }
}

// ---------------- fused loss v2: whole 512-row P in registers ----------------
// ONE z-stream per (b,k): 768 blocks total (vs r2's 3072 streaming passes).
// Phase 1: P = ch(b) @ Wp[k] computed in 4x128-row chunks through a reusable
// Pst LDS buffer; each wave keeps A-fragments for its 16 rows of every chunk
// in registers (16 x bf16x8 = 64 VGPR) + the sS-dot per row. Phase 2: stream
// z ONCE with LDS-double-buffered Zt (1 barrier/ct-iter, reg-prefetch 2 tiles
// ahead); 64 MFMA per wave per ct-iter (4x r2's per-barrier matrix work).
// Grid order b-fastest: the 4+ co-running k-blocks of one b share zh[b]/ch(b)
// in L2.
__global__ __attribute__((amdgpu_flat_work_group_size(512, 512)))
void loss_fused(const u16* __restrict__ ch,
                const u16* __restrict__ Wpt,
                const float* __restrict__ bp,
                const u16* __restrict__ zh,
                const float* __restrict__ zsum,
                float* __restrict__ accum) {
    __shared__ u16 Pst[128][136];        // 34816 B (reused per chunk)
    __shared__ u16 Zt[2][64][136];       // 34816 B (double buffer)
    __shared__ float sS[128];
    __shared__ float red[8];
    int b  = blockIdx.x;
    int kz = blockIdx.y;                 // 0..11
    int k  = kz + 1;
    int Tk = T_ - k;
    int tid  = threadIdx.x;              // 0..511
    int w    = tid >> 6;
    int lane = tid & 63;
    int col  = lane & 15;
    int quad = lane >> 4;
    const u16* zb = zh + (size_t)b * T_ * P_;

    // S_bk
    if (tid < 128) {
        float s = zsum[(size_t)b * P_ + tid];
        for (int t = 1; t < k; t++) s -= bf2f(zb[(size_t)t * P_ + tid]);
        sS[tid] = s;
    }

    // ---- phase 1: P chunks -> register A-fragments + d-dot ------------------
    bf16x8 pfrag[4][4];                  // [chunk][k0] : 64 VGPR
    float  dreg[4][4];                   // [chunk][r]
    const u16* wk = Wpt + (size_t)kz * P_ * H_;
    #pragma unroll
    for (int c = 0; c < 4; c++) {
        f32x4 acc[8] = {};
        const u16* arow = ch + ((size_t)b * T_ + c * 128 + w * 16 + col) * H_;
        #pragma unroll
        for (int k0 = 0; k0 < 8; k0++) {
            bf16x8 af = *(const bf16x8*)(arow + k0 * 32 + quad * 8);
            #pragma unroll
            for (int nt = 0; nt < 8; nt++) {
                bf16x8 bf = *(const bf16x8*)(wk + (size_t)(nt * 16 + col) * H_ + k0 * 32 + quad * 8);
                acc[nt] = __builtin_amdgcn_mfma_f32_16x16x32_bf16(af, bf, acc[nt], 0, 0, 0);
            }
        }
        __syncthreads();                 // Pst free (prev chunk's reads done)
        #pragma unroll
        for (int nt = 0; nt < 8; nt++) {
            float bias = bp[(size_t)kz * P_ + nt * 16 + col];
            #pragma unroll
            for (int r = 0; r < 4; r++)
                Pst[w * 16 + quad * 4 + r][nt * 16 + col] = f2bf(acc[nt][r] + bias);
        }
        __syncthreads();
        // A-fragments for phase 2 (row = lane&15 within the wave's 16 rows)
        #pragma unroll
        for (int k0 = 0; k0 < 4; k0++)
            pfrag[c][k0] = *(const bf16x8*)(&Pst[w * 16 + col][k0 * 32 + quad * 8]);
        // d = P-row . sS  (sS ready: written before first barrier)
        #pragma unroll
        for (int r = 0; r < 4; r++) {
            BF8 pv;
            pv.v = *(const bf16x8*)(&Pst[w * 16 + quad * 4 + r][col * 8]);
            float d = 0.f;
            #pragma unroll
            for (int m = 0; m < 8; m++) d = fmaf(bf2f(pv.e[m]), sS[col * 8 + m], d);
            #pragma unroll
            for (int o = 1; o < 16; o <<= 1) d += __shfl_xor(d, o, 64);
            dreg[c][r] = d;
        }
    }

    // ---- phase 2: single z-stream, LDS-double-buffered Zt -------------------
    float mloc[4][4], sloc[4][4];
    #pragma unroll
    for (int c = 0; c < 4; c++)
        #pragma unroll
        for (int r = 0; r < 4; r++) { mloc[c][r] = -INFINITY; sloc[c][r] = 0.f; }

    int rr  = tid >> 4;                  // 0..31
    int off = (tid & 15) * 8;
    const u16* zk = zb + (size_t)k * P_;
    // tile 0 -> Zt[0]; prefetch tile 1 (over-reads masked + land in slack)
    {
        uint4 a0 = *(const uint4*)(zk + (size_t)rr * P_ + off);
        uint4 b0 = *(const uint4*)(zk + (size_t)(rr + 32) * P_ + off);
        *(uint4*)&Zt[0][rr][off]      = a0;
        *(uint4*)&Zt[0][rr + 32][off] = b0;
    }
    uint4 rA = *(const uint4*)(zk + (size_t)(64 + rr) * P_ + off);
    uint4 rB = *(const uint4*)(zk + (size_t)(64 + rr + 32) * P_ + off);
    __syncthreads();

    int cb = 0;
    #pragma unroll 1
    for (int it = 0; it < 8; ++it) {
        const u16* ztb = &Zt[cb][0][0];
        f32x4 acc[4][4] = {};            // [chunk][nt] : 64 VGPR
        #pragma unroll
        for (int k0 = 0; k0 < 4; k0++) {
            #pragma unroll
            for (int nt = 0; nt < 4; nt++) {
                bf16x8 bf = *(const bf16x8*)(ztb + (size_t)(nt * 16 + col) * 136 + k0 * 32 + quad * 8);
                acc[0][nt] = __builtin_amdgcn_mfma_f32_16x16x32_bf16(pfrag[0][k0], bf, acc[0][nt], 0, 0, 0);
                acc[1][nt] = __builtin_amdgcn_mfma_f32_16x16x32_bf16(pfrag[1][k0], bf, acc[1][nt], 0, 0, 0);
                acc[2][nt] = __builtin_amdgcn_mfma_f32_16x16x32_bf16(pfrag[2][k0], bf, acc[2][nt], 0, 0, 0);
                acc[3][nt] = __builtin_amdgcn_mfma_f32_16x16x32_bf16(pfrag[3][k0], bf, acc[3][nt], 0, 0, 0);
            }
        }
        // stage next tile into the other buffer; prefetch tile it+2
        if (it < 7) {
            *(uint4*)&Zt[cb ^ 1][rr][off]      = rA;
            *(uint4*)&Zt[cb ^ 1][rr + 32][off] = rB;
            if (it < 6) {
                const u16* zn = zk + (size_t)((it + 2) * 64) * P_;
                rA = *(const uint4*)(zn + (size_t)rr * P_ + off);
                rB = *(const uint4*)(zn + (size_t)(rr + 32) * P_ + off);
            }
        }
        int ct = it * 64;
        #pragma unroll
        for (int c = 0; c < 4; c++) {
            #pragma unroll
            for (int r = 0; r < 4; r++) {
                float l[4];
                float tmax = -INFINITY;
                #pragma unroll
                for (int nt = 0; nt < 4; nt++) {
                    int cc = ct + nt * 16 + col;
                    l[nt] = (cc < Tk) ? acc[c][nt][r] * INV_TEMP : -INFINITY;
                    tmax = fmaxf(tmax, l[nt]);
                }
                float mnew = fmaxf(mloc[c][r], tmax);
                float e = __expf(l[0] - mnew) + __expf(l[1] - mnew)
                        + __expf(l[2] - mnew) + __expf(l[3] - mnew);
                sloc[c][r] = sloc[c][r] * __expf(mloc[c][r] - mnew) + e;
                mloc[c][r] = mnew;
            }
        }
        __syncthreads();
        cb ^= 1;
    }

    // merge LSE across the 16-lane col groups
    #pragma unroll
    for (int c = 0; c < 4; c++)
        #pragma unroll
        for (int r = 0; r < 4; r++) {
            #pragma unroll
            for (int o = 1; o < 16; o <<= 1) {
                float mo = __shfl_xor(mloc[c][r], o, 64);
                float so = __shfl_xor(sloc[c][r], o, 64);
                float mn = fmaxf(mloc[c][r], mo);
                sloc[c][r] = sloc[c][r] * __expf(mloc[c][r] - mn) + so * __expf(mo - mn);
                mloc[c][r] = mn;
            }
        }
    float tkinv = INV_TEMP / (float)Tk;
    float scale = 1.0f / ((float)K_ * (float)B_ * (float)Tk);
    float bs = 0.f;
    #pragma unroll
    for (int c = 0; c < 4; c++)
        #pragma unroll
        for (int r = 0; r < 4; r++) {
            int gr = c * 128 + w * 16 + quad * 4 + r;
            if (gr < Tk) bs += mloc[c][r] + __logf(sloc[c][r]) - dreg[c][r] * tkinv;
        }
    if (col != 0) bs = 0.f;
    bs = wave_sum(bs);
    if (lane == 0) red[w] = bs;
    __syncthreads();
    if (tid == 0) {
        float tot = 0.f;
        #pragma unroll
        for (int i = 0; i < 8; i++) tot += red[i];
        atomicAdd(&accum[(b * 67 + kz * 131) & 1023], tot * scale);
    }
}

__global__ void finalize(const float* __restrict__ accum, float* __restrict__ out) {
    int tid = threadIdx.x;
    __shared__ float red[4];
    float v = 0.f;
    for (int i = tid; i < 1024; i += 256) v += accum[i];
    float sres = wave_sum(v);
    if ((tid & 63) == 0) red[tid >> 6] = sres;
    __syncthreads();
    if (tid == 0) out[0] = red[0] + red[1] + red[2] + red[3];
}

// ---------------- launch -----------------------------------------------------
extern "C" void kernel_launch(void* const* d_in, const int* in_sizes, int n_in,
                              void* d_out, int out_size, void* d_ws, size_t ws_size,
                              hipStream_t stream) {
    const float* x      = (const float*)d_in[0];
    const float* W_enc  = (const float*)d_in[1];
    const float* b_enc  = (const float*)d_in[2];
    const float* W_proj = (const float*)d_in[3];
    const float* b_proj = (const float*)d_in[4];
    const float* Wi     = (const float*)d_in[5];
    const float* bi     = (const float*)d_in[6];
    const float* Wh     = (const float*)d_in[7];
    const float* bhn    = (const float*)d_in[8];
    const float* Wp     = (const float*)d_in[9];
    const float* bp     = (const float*)d_in[10];
    float* out = (float*)d_out;

    // layout (float offsets)
    float* ws    = (float*)d_ws;
    float* bc    = ws;                          // 128
    float* accum = bc + 128;                    // 1024 -> end 1152
    _Float16* Wht = (_Float16*)(ws + 1152);     // 196608 f16 = 98304 fl -> end 99456
    u16* Wct     = (u16*)(ws + 99456);          // 16384 fl -> end 115840
    u16* Wit     = (u16*)(ws + 115840);         // 49152 fl -> end 164992
    u16* Wpt     = (u16*)(ws + 164992);         // 196608 fl -> end 361600
    u16* zh      = (u16*)(ws + 361600);         // 2097152 fl -> end 2458752
    float* zsum  = ws + 2458752;                // 8192 fl (doubles as zh over-read slack) -> end 2466944
    u16* gi      = (u16*)(ws + 2466944);        // 12582912 fl -> end 15049856
    u16* ch      = (u16*)(ws + 15049856);       // 4194304 fl -> end 19244160 (~77 MB)

    const int MT = B_ * T_;                     // 32768

    // merged setup: all weight conversions + fold + accum zero (801 blocks)
    setup_conv<<<801, 256, 0, stream>>>(Wh, Wht, Wi, Wit, Wp, Wpt,
                                        W_enc, b_enc, W_proj, b_proj, Wct, bc, accum);
    // zh = bf16(x @ Wct^T + bc)   (M=32768, N=128, K=256; A converted in-reg)
    gemm_mfma_f32a<<<dim3(1, MT / 64), 256, 0, stream>>>(x, Wct, bc, zh, P_, F_);
    // gi = bf16(zh @ Wit^T + bi)  (M=32768, N=768, K=128)
    gemm_mfma<<<dim3(6, MT / 64), 256, 0, stream>>>(zh, Wit, bi, gi, 3 * H_, P_);
    // GRU scan (blocks 0..63) + zsum (64..127) — r2-proven structure
    gru_zsum_kernel<<<GRUB_ + B_, 512, 0, stream>>>(gi, Wht, bhn, ch, zh, zsum);
    // fused loss v2: one z-stream per (b,k); P in registers; 768 blocks
    loss_fused<<<dim3(B_, K_), 512, 0, stream>>>(ch, Wpt, bp, zh, zsum, accum);
    finalize<<<1, 256, 0, stream>>>(accum, out);
}

// Round 9
// 967.808 us; speedup vs baseline: 1.1252x; 1.0786x over previous
//
#include <hip/hip_runtime.h>
#include <hip/hip_bf16.h>
#include <math.h>

#define B_   64
#define T_   512
#define F_   256
#define ENC_ 256
#define P_   128
#define H_   256
#define K_   12
#define INV_TEMP 10.0f

typedef unsigned short u16;
typedef _Float16 half2v __attribute__((ext_vector_type(2)));
union U2H { unsigned int u; half2v h; };
typedef __attribute__((ext_vector_type(8))) short bf16x8;   // 8 bf16 = 4 VGPRs
typedef __attribute__((ext_vector_type(4))) float f32x4;    // MFMA C/D
typedef _Float16 f16x8 __attribute__((ext_vector_type(8))); // 8 f16 = 4 VGPRs
union BF8 { bf16x8 v; u16 e[8]; };

// ---------------- helpers ----------------------------------------------------
__device__ __forceinline__ float rcpf(float x) {
#if __has_builtin(__builtin_amdgcn_rcpf)
    return __builtin_amdgcn_rcpf(x);
#else
    return 1.f / x;
#endif
}
__device__ __forceinline__ u16 f2bf(float f) {   // RNE
    unsigned int u = __float_as_uint(f);
    unsigned int r = (u + 0x7fffu + ((u >> 16) & 1u)) >> 16;
    return (u16)r;
}
__device__ __forceinline__ float bf2f(u16 v) {
    return __uint_as_float(((unsigned int)v) << 16);
}
__device__ __forceinline__ float bflo(unsigned int u) { return __uint_as_float(u << 16); }
__device__ __forceinline__ float bfhi(unsigned int u) { return __uint_as_float(u & 0xffff0000u); }
__device__ __forceinline__ float wave_sum(float v) {
    #pragma unroll
    for (int o = 32; o > 0; o >>= 1) v += __shfl_down(v, o, 64);
    return v;
}

// ---------------- merged setup: weight conversions + fold + accum zero -------
__global__ __launch_bounds__(256) void setup_conv(const float* __restrict__ Wh,
                                                  _Float16* __restrict__ Wht,
                                                  const float* __restrict__ Wi,
                                                  u16* __restrict__ Wit,
                                                  const float* __restrict__ Wp,
                                                  u16* __restrict__ Wpt,
                                                  const float* __restrict__ We,
                                                  const float* __restrict__ be,
                                                  const float* __restrict__ Wpj,
                                                  const float* __restrict__ bpj,
                                                  u16* __restrict__ Wct,
                                                  float* __restrict__ bc,
                                                  float* __restrict__ accum) {
    int bid = blockIdx.x;
    if (bid < 192) {
        // Wht[g][k] = (f16)Wh[k][g]  (768x256 out of 256x768 in; 24x8 32x32 tiles)
        __shared__ float tile0[32][33];
        int g0 = (bid % 24) * 32, k0 = (bid / 24) * 32;
        int tx = threadIdx.x & 31, ty = threadIdx.x >> 5;
        #pragma unroll
        for (int i = 0; i < 32; i += 8)
            tile0[ty + i][tx] = Wh[(size_t)(k0 + ty + i) * 768 + g0 + tx];
        __syncthreads();
        #pragma unroll
        for (int i = 0; i < 32; i += 8)
            Wht[(size_t)(g0 + ty + i) * 256 + k0 + tx] = (_Float16)tile0[tx][ty + i];
    } else if (bid < 288) {
        __shared__ float tile[32][33];
        int b2 = bid - 192;                       // 0..95
        int n0 = (b2 % 24) * 32, k0 = (b2 / 24) * 32;
        int tx = threadIdx.x & 31, ty = threadIdx.x >> 5;
        #pragma unroll
        for (int i = 0; i < 32; i += 8)
            tile[ty + i][tx] = Wi[(size_t)(k0 + ty + i) * 768 + n0 + tx];
        __syncthreads();
        #pragma unroll
        for (int i = 0; i < 32; i += 8)
            Wit[(size_t)(n0 + ty + i) * 128 + k0 + tx] = f2bf(tile[tx][ty + i]);
    } else if (bid < 672) {
        __shared__ float tile2[32][33];
        int b3 = bid - 288;                       // 0..383
        int kq = b3 / 32, rem = b3 % 32;
        int h0 = (rem % 8) * 32, p0 = (rem / 8) * 32;
        int tx = threadIdx.x & 31, ty = threadIdx.x >> 5;
        #pragma unroll
        for (int i = 0; i < 32; i += 8)
            tile2[ty + i][tx] = Wp[(size_t)kq * H_ * P_ + (size_t)(h0 + ty + i) * P_ + p0 + tx];
        __syncthreads();
        #pragma unroll
        for (int i = 0; i < 32; i += 8)
            Wpt[(size_t)kq * P_ * H_ + (size_t)(p0 + ty + i) * H_ + h0 + tx] = f2bf(tile2[tx][ty + i]);
    } else {
        // fold: f = 2*(bid-672) + (tid>>7); p = tid&127
        int f = (bid - 672) * 2 + (threadIdx.x >> 7);
        int p = threadIdx.x & 127;
        if (f < F_) {
            float a = 0.f;
            for (int e = 0; e < ENC_; e++) a = fmaf(We[f * ENC_ + e], Wpj[e * P_ + p], a);
            Wct[(size_t)p * F_ + f] = f2bf(a);
        } else if (f == F_) {
            float a = bpj[p];
            for (int e = 0; e < ENC_; e++) a = fmaf(be[e], Wpj[e * P_ + p], a);
            bc[p] = a;
        } else {
            #pragma unroll
            for (int i = 0; i < 8; i++) accum[p * 8 + i] = 0.f;
        }
    }
}

// ---------------- MFMA GEMM, A = fp32 (converted in-register) ----------------
__global__ __launch_bounds__(256) void gemm_mfma_f32a(const float* __restrict__ A,
                                                      const u16* __restrict__ Bt,
                                                      const float* __restrict__ bias,
                                                      u16* __restrict__ Ch,
                                                      int N, int K) {
    int tid  = threadIdx.x;
    int w    = tid >> 6;
    int lane = tid & 63;
    int col  = lane & 15;
    int quad = lane >> 4;
    int bm = blockIdx.y * 64, bn = blockIdx.x * 128;

    f32x4 acc[8] = {};
    const float* arow = A + (size_t)(bm + w * 16 + col) * K;
    #pragma unroll
    for (int k0 = 0; k0 < K; k0 += 32) {
        float4 v0 = *(const float4*)(arow + k0 + quad * 8);
        float4 v1 = *(const float4*)(arow + k0 + quad * 8 + 4);
        BF8 af;
        af.e[0] = f2bf(v0.x); af.e[1] = f2bf(v0.y); af.e[2] = f2bf(v0.z); af.e[3] = f2bf(v0.w);
        af.e[4] = f2bf(v1.x); af.e[5] = f2bf(v1.y); af.e[6] = f2bf(v1.z); af.e[7] = f2bf(v1.w);
        #pragma unroll
        for (int nt = 0; nt < 8; nt++) {
            bf16x8 bf = *(const bf16x8*)(Bt + (size_t)(bn + nt * 16 + col) * K + k0 + quad * 8);
            acc[nt] = __builtin_amdgcn_mfma_f32_16x16x32_bf16(af.v, bf, acc[nt], 0, 0, 0);
        }
    }
    #pragma unroll
    for (int nt = 0; nt < 8; nt++) {
        int gn = bn + nt * 16 + col;
        float bv = bias[gn];
        #pragma unroll
        for (int r = 0; r < 4; r++) {
            int gm = bm + w * 16 + quad * 4 + r;
            Ch[(size_t)gm * N + gn] = f2bf(acc[nt][r] + bv);
        }
    }
}

// ---------------- MFMA GEMM, A = bf16, C = bf16 ------------------------------
__global__ __launch_bounds__(256) void gemm_mfma(const u16* __restrict__ A,
                                                 const u16* __restrict__ Bt,
                                                 const float* __restrict__ bias,
                                                 u16* __restrict__ Ch,
                                                 int N, int K) {
    int tid  = threadIdx.x;
    int w    = tid >> 6;
    int lane = tid & 63;
    int col  = lane & 15;
    int quad = lane >> 4;
    int bm = blockIdx.y * 64, bn = blockIdx.x * 128;

    f32x4 acc[8] = {};
    const u16* arow = A + (size_t)(bm + w * 16 + col) * K;
    #pragma unroll
    for (int k0 = 0; k0 < K; k0 += 32) {
        bf16x8 af = *(const bf16x8*)(arow + k0 + quad * 8);
        #pragma unroll
        for (int nt = 0; nt < 8; nt++) {
            bf16x8 bf = *(const bf16x8*)(Bt + (size_t)(bn + nt * 16 + col) * K + k0 + quad * 8);
            acc[nt] = __builtin_amdgcn_mfma_f32_16x16x32_bf16(af, bf, acc[nt], 0, 0, 0);
        }
    }
    #pragma unroll
    for (int nt = 0; nt < 8; nt++) {
        int gn = bn + nt * 16 + col;
        float bv = bias[gn];
        #pragma unroll
        for (int r = 0; r < 4; r++) {
            int gm = bm + w * 16 + quad * 4 + r;
            Ch[(size_t)gm * N + gn] = f2bf(acc[nt][r] + bv);
        }
    }
}

// ---------------- GRU scan (blocks 0..63) + zsum (blocks 64..127) ------------
// r2-proven structure: MFMA recurrence, M=16 replicated rows, 1 batch/block.
#define GRUB_ 64

__global__ __attribute__((amdgpu_flat_work_group_size(512, 512)))
void gru_zsum_kernel(const u16* __restrict__ gi,
                     const _Float16* __restrict__ Wht,
                     const float* __restrict__ bhn,
                     u16* __restrict__ ch,
                     const u16* __restrict__ zh,
                     float* __restrict__ zsum) {
    __shared__ __align__(16) char smem[8704];
    int tid = threadIdx.x;          // 0..511

    if (blockIdx.x >= GRUB_) {
        // ---- zsum[b][p] = sum_{t=1..T-1} z[b][t][p], 16-way t-split ---------
        float (*part)[128] = (float (*)[128])smem;   // 8192 B
        int b   = blockIdx.x - GRUB_;
        int pg  = tid & 31;
        int g   = tid >> 5;
        const u16* zb = zh + (size_t)b * T_ * P_;
        float s0 = 0.f, s1 = 0.f, s2 = 0.f, s3 = 0.f;
        for (int t = 1 + g; t < T_; t += 16) {
            uint2 v = *(const uint2*)(zb + (size_t)t * P_ + pg * 4);
            s0 += bflo(v.x); s1 += bfhi(v.x);
            s2 += bflo(v.y); s3 += bfhi(v.y);
        }
        part[g][pg * 4 + 0] = s0; part[g][pg * 4 + 1] = s1;
        part[g][pg * 4 + 2] = s2; part[g][pg * 4 + 3] = s3;
        __syncthreads();
        if (tid < 128) {
            float s = 0.f;
            #pragma unroll
            for (int g2 = 0; g2 < 16; g2++) s += part[g2][tid];
            zsum[(size_t)b * P_ + tid] = s;
        }
        return;
    }

    // ---- GRU, 1 batch/block -------------------------------------------------
    _Float16* hbase = (_Float16*)smem;           // [2][264] f16 double buffer

    int lane = tid & 63, w = tid >> 6;
    int col  = lane & 15, quad = lane >> 4;
    int b    = blockIdx.x;
    int jj0  = w * 32 + col;                     // n2=0 gate-col; n2=1 adds 16

    f16x8 wf[3][2][8];
    #pragma unroll
    for (int g = 0; g < 3; g++)
        #pragma unroll
        for (int n2 = 0; n2 < 2; n2++) {
            const _Float16* src = Wht + (size_t)(g * 256 + jj0 + n2 * 16) * 256 + quad * 8;
            #pragma unroll
            for (int k0 = 0; k0 < 8; k0++)
                wf[g][n2][k0] = *(const f16x8*)(src + k0 * 32);
        }
    #pragma unroll
    for (int g = 0; g < 3; g++)
        #pragma unroll
        for (int n2 = 0; n2 < 2; n2++)
            #pragma unroll
            for (int k0 = 0; k0 < 8; k0++)
                asm volatile("" : "+v"(wf[g][n2][k0]));

    for (int i = tid; i < 528; i += 512) hbase[i] = (_Float16)0.f;

    const u16* gb = gi + (size_t)b * T_ * 768;
    u16* cb       = ch + (size_t)b * T_ * 256;
    float bh0 = bhn[jj0], bh1 = bhn[jj0 + 16];
    float hold0 = 0.f, hold1 = 0.f;
    unsigned int pf[6];

    {   // preload t=0 gate inputs
        pf[0] = gb[jj0];        pf[1] = gb[jj0 + 16];
        pf[2] = gb[256 + jj0];  pf[3] = gb[256 + jj0 + 16];
        pf[4] = gb[512 + jj0];  pf[5] = gb[512 + jj0 + 16];
    }
    __syncthreads();     // h zeros visible (one-time full drain is fine)

    auto body = [&](int t, int c) {
        int n = c ^ 1;
        const _Float16* HC = hbase + c * 264;
        _Float16*       HN = hbase + n * 264;
        f32x4 aR0 = {}, aR1 = {}, aZ0 = {}, aZ1 = {}, aN0 = {}, aN1 = {};
        #pragma unroll
        for (int k0 = 0; k0 < 8; k0++) {
            f16x8 af = *(const f16x8*)(HC + k0 * 32 + quad * 8);   // broadcast read
            aR0 = __builtin_amdgcn_mfma_f32_16x16x32_f16(af, wf[0][0][k0], aR0, 0, 0, 0);
            aR1 = __builtin_amdgcn_mfma_f32_16x16x32_f16(af, wf[0][1][k0], aR1, 0, 0, 0);
            aZ0 = __builtin_amdgcn_mfma_f32_16x16x32_f16(af, wf[1][0][k0], aZ0, 0, 0, 0);
            aZ1 = __builtin_amdgcn_mfma_f32_16x16x32_f16(af, wf[1][1][k0], aZ1, 0, 0, 0);
            aN0 = __builtin_amdgcn_mfma_f32_16x16x32_f16(af, wf[2][0][k0], aN0, 0, 0, 0);
            aN1 = __builtin_amdgcn_mfma_f32_16x16x32_f16(af, wf[2][1][k0], aN1, 0, 0, 0);
        }
        float rg0 = rcpf(1.f + __expf(-(bf2f((u16)pf[0]) + aR0[0])));
        float rg1 = rcpf(1.f + __expf(-(bf2f((u16)pf[1]) + aR1[0])));
        float zg0 = rcpf(1.f + __expf(-(bf2f((u16)pf[2]) + aZ0[0])));
        float zg1 = rcpf(1.f + __expf(-(bf2f((u16)pf[3]) + aZ1[0])));
        float xn0 = bf2f((u16)pf[4]) + rg0 * (aN0[0] + bh0);
        float xn1 = bf2f((u16)pf[5]) + rg1 * (aN1[0] + bh1);
        float nn0 = fmaf(2.f, rcpf(1.f + __expf(-2.f * xn0)), -1.f);
        float nn1 = fmaf(2.f, rcpf(1.f + __expf(-2.f * xn1)), -1.f);
        hold0 = (1.f - zg0) * nn0 + zg0 * hold0;
        hold1 = (1.f - zg1) * nn1 + zg1 * hold1;
        if (quad == 0) {                 // LDS h for next step
            HN[jj0]      = (_Float16)hold0;
            HN[jj0 + 16] = (_Float16)hold1;
        } else if (quad == 1) {          // global ch (redundant copies identical)
            u16* cr = cb + (size_t)t * 256;
            cr[jj0]      = f2bf(hold0);
            cr[jj0 + 16] = f2bf(hold1);
        }
        if (t + 1 < T_) {
            const u16* gr = gb + (size_t)(t + 1) * 768;
            pf[0] = gr[jj0];        pf[1] = gr[jj0 + 16];
            pf[2] = gr[256 + jj0];  pf[3] = gr[256 + jj0 + 16];
            pf[4] = gr[512 + jj0];  pf[5] = gr[512 + jj0 + 16];
        }
        asm volatile("s_waitcnt lgkmcnt(0)" ::: "memory");
        __builtin_amdgcn_s_barrier();
        asm volatile("" ::: "memory");
    };

    #pragma unroll 1
    for (int t = 0; t < T_; t += 2) {
        body(t,     0);
        body(t + 1, 1);
    }
}

// ---------------- fused loss (r2 skeleton + occupancy/barrier fix) -----------
// r8 post-mortem: all loss variants (276-314us) sit 3x above the compute model
// (~100us) -> latency x serial-rounds bound, not pipe/traffic bound. Fix:
// (1) __launch_bounds__(512,4) caps VGPR at 128 -> 4 waves/SIMD -> 2 blocks/CU
//     co-resident (LDS 70KB fits): halves serial rounds, lets block A's softmax
//     overlap block B's MFMA (m114).
// (2) Zt double buffer -> ONE barrier per ct-iter (write staged regs at iter
//     top, loads issued 2 tiles ahead -> always latency-covered).
__global__ __launch_bounds__(512, 4) void loss_fused(const u16* __restrict__ ch,
                                                     const u16* __restrict__ Wpt,
                                                     const float* __restrict__ bp,
                                                     const u16* __restrict__ zh,
                                                     const float* __restrict__ zsum,
                                                     float* __restrict__ accum) {
    __shared__ u16 Pst[128][136];        // 34816 B
    __shared__ u16 Zt[2][64][136];       // 34816 B (double buffer)
    __shared__ float sS[128];
    __shared__ float red[8];
    int k  = blockIdx.z + 1;
    int b  = blockIdx.y;
    int t0 = blockIdx.x * 128;
    int Tk = T_ - k;
    int tid  = threadIdx.x;
    int w    = tid >> 6;
    int lane = tid & 63;
    int col  = lane & 15;
    int quad = lane >> 4;
    const u16* zb = zh + (size_t)b * T_ * P_;
    const u16* zk = zb + (size_t)k * P_;

    // issue first 2 z-tiles ASAP (latency hidden under S_bk + phase 1)
    int rr  = tid >> 4;                  // 0..31
    int off = (tid & 15) * 8;
    uint4 a0 = *(const uint4*)(zk + (size_t)rr * P_ + off);
    uint4 b0 = *(const uint4*)(zk + (size_t)(rr + 32) * P_ + off);
    uint4 rA = *(const uint4*)(zk + (size_t)(64 + rr) * P_ + off);
    uint4 rB = *(const uint4*)(zk + (size_t)(64 + rr + 32) * P_ + off);

    // S_bk = zsum_b - sum_{t=1}^{k-1} z[t]
    if (tid < 128) {
        float s = zsum[(size_t)b * P_ + tid];
        for (int t = 1; t < k; t++) s -= bf2f(zb[(size_t)t * P_ + tid]);
        sS[tid] = s;
    }

    // ---- phase 1: Pst = bf16(ch-tile @ Wp[k] + bp[k]) -----------------------
    {
        f32x4 acc[8] = {};
        const u16* arow = ch + ((size_t)b * T_ + t0 + w * 16 + col) * H_;
        const u16* wk   = Wpt + (size_t)(k - 1) * P_ * H_;
        #pragma unroll
        for (int k0 = 0; k0 < 8; k0++) {
            bf16x8 af = *(const bf16x8*)(arow + k0 * 32 + quad * 8);
            #pragma unroll
            for (int nt = 0; nt < 8; nt++) {
                bf16x8 bf = *(const bf16x8*)(wk + (size_t)(nt * 16 + col) * H_ + k0 * 32 + quad * 8);
                acc[nt] = __builtin_amdgcn_mfma_f32_16x16x32_bf16(af, bf, acc[nt], 0, 0, 0);
            }
        }
        #pragma unroll
        for (int nt = 0; nt < 8; nt++) {
            float bias = bp[(size_t)(k - 1) * P_ + nt * 16 + col];
            #pragma unroll
            for (int r = 0; r < 4; r++)
                Pst[w * 16 + quad * 4 + r][nt * 16 + col] = f2bf(acc[nt][r] + bias);
        }
        // stage z tile 0 while phase-1 epilogue runs
        *(uint4*)&Zt[0][rr][off]      = a0;
        *(uint4*)&Zt[0][rr + 32][off] = b0;
    }
    __syncthreads();

    // ---- phase 2: flash LSE, double-buffered Zt, 1 barrier/iter -------------
    float mloc[4], sloc[4];
    #pragma unroll
    for (int r = 0; r < 4; r++) { mloc[r] = -INFINITY; sloc[r] = 0.f; }

    int nIter = (Tk + 63) >> 6;          // 8 for all k<=12
    int cbuf = 0;
    #pragma unroll 1
    for (int it = 0; it < nIter; ++it) {
        // write tile it+1 (loaded >=1 iter ago) into the other buffer
        if (it + 1 < nIter) {
            *(uint4*)&Zt[cbuf ^ 1][rr][off]      = rA;
            *(uint4*)&Zt[cbuf ^ 1][rr + 32][off] = rB;
        }
        // issue loads for tile it+2 (over-read past T lands in slack, masked)
        if (it + 2 < nIter) {
            const u16* zn = zk + (size_t)((it + 2) * 64) * P_;
            rA = *(const uint4*)(zn + (size_t)rr * P_ + off);
            rB = *(const uint4*)(zn + (size_t)(rr + 32) * P_ + off);
        }
        // MFMA on current buffer
        const u16* ztb = &Zt[cbuf][0][0];
        f32x4 acc[4] = {};
        #pragma unroll
        for (int k0 = 0; k0 < 4; k0++) {
            bf16x8 af = *(const bf16x8*)(&Pst[w * 16 + col][k0 * 32 + quad * 8]);
            #pragma unroll
            for (int nt = 0; nt < 4; nt++) {
                bf16x8 bf = *(const bf16x8*)(ztb + (size_t)(nt * 16 + col) * 136 + k0 * 32 + quad * 8);
                acc[nt] = __builtin_amdgcn_mfma_f32_16x16x32_bf16(af, bf, acc[nt], 0, 0, 0);
            }
        }
        int ct = it * 64;
        #pragma unroll
        for (int r = 0; r < 4; r++) {
            float l[4];
            float tmax = -INFINITY;
            #pragma unroll
            for (int nt = 0; nt < 4; nt++) {
                bool valid = (ct + nt * 16 + col) < Tk;
                l[nt] = valid ? acc[nt][r] * INV_TEMP : -INFINITY;
                tmax = fmaxf(tmax, l[nt]);
            }
            float mnew = fmaxf(mloc[r], tmax);
            float e = __expf(l[0] - mnew) + __expf(l[1] - mnew)
                    + __expf(l[2] - mnew) + __expf(l[3] - mnew);
            sloc[r] = sloc[r] * __expf(mloc[r] - mnew) + e;
            mloc[r] = mnew;
        }
        asm volatile("s_waitcnt lgkmcnt(0)" ::: "memory");
        __builtin_amdgcn_s_barrier();
        asm volatile("" ::: "memory");
        cbuf ^= 1;
    }
    #pragma unroll
    for (int r = 0; r < 4; r++) {
        #pragma unroll
        for (int o = 1; o < 16; o <<= 1) {
            float mo = __shfl_xor(mloc[r], o, 64);
            float so = __shfl_xor(sloc[r], o, 64);
            float mn = fmaxf(mloc[r], mo);
            sloc[r] = sloc[r] * __expf(mloc[r] - mn) + so * __expf(mo - mn);
            mloc[r] = mn;
        }
    }
    float tkinv = INV_TEMP / (float)Tk;
    float scale = 1.0f / ((float)K_ * (float)B_ * (float)Tk);
    float bs = 0.f;
    #pragma unroll
    for (int r = 0; r < 4; r++) {
        int row = w * 16 + quad * 4 + r;
        BF8 pv;
        pv.v = *(const bf16x8*)(&Pst[row][col * 8]);
        float d = 0.f;
        #pragma unroll
        for (int m = 0; m < 8; m++) d = fmaf(bf2f(pv.e[m]), sS[col * 8 + m], d);
        #pragma unroll
        for (int o = 1; o < 16; o <<= 1) d += __shfl_xor(d, o, 64);
        int gr = t0 + row;
        if (gr < Tk) bs += mloc[r] + __logf(sloc[r]) - d * tkinv;
    }
    if (col != 0) bs = 0.f;
    bs = wave_sum(bs);
    if (lane == 0) red[w] = bs;
    __syncthreads();
    if (tid == 0) {
        float tot = 0.f;
        #pragma unroll
        for (int i = 0; i < 8; i++) tot += red[i];
        atomicAdd(&accum[(blockIdx.x * 809 + b * 67 + blockIdx.z * 131) & 1023],
                  tot * scale);
    }
}

__global__ void finalize(const float* __restrict__ accum, float* __restrict__ out) {
    int tid = threadIdx.x;
    __shared__ float red[4];
    float v = 0.f;
    for (int i = tid; i < 1024; i += 256) v += accum[i];
    float sres = wave_sum(v);
    if ((tid & 63) == 0) red[tid >> 6] = sres;
    __syncthreads();
    if (tid == 0) out[0] = red[0] + red[1] + red[2] + red[3];
}

// ---------------- launch -----------------------------------------------------
extern "C" void kernel_launch(void* const* d_in, const int* in_sizes, int n_in,
                              void* d_out, int out_size, void* d_ws, size_t ws_size,
                              hipStream_t stream) {
    const float* x      = (const float*)d_in[0];
    const float* W_enc  = (const float*)d_in[1];
    const float* b_enc  = (const float*)d_in[2];
    const float* W_proj = (const float*)d_in[3];
    const float* b_proj = (const float*)d_in[4];
    const float* Wi     = (const float*)d_in[5];
    const float* bi     = (const float*)d_in[6];
    const float* Wh     = (const float*)d_in[7];
    const float* bhn    = (const float*)d_in[8];
    const float* Wp     = (const float*)d_in[9];
    const float* bp     = (const float*)d_in[10];
    float* out = (float*)d_out;

    // layout (float offsets)
    float* ws    = (float*)d_ws;
    float* bc    = ws;                          // 128
    float* accum = bc + 128;                    // 1024 -> end 1152
    _Float16* Wht = (_Float16*)(ws + 1152);     // 196608 f16 = 98304 fl -> end 99456
    u16* Wct     = (u16*)(ws + 99456);          // 16384 fl -> end 115840
    u16* Wit     = (u16*)(ws + 115840);         // 49152 fl -> end 164992
    u16* Wpt     = (u16*)(ws + 164992);         // 196608 fl -> end 361600
    u16* zh      = (u16*)(ws + 361600);         // 2097152 fl -> end 2458752
    float* zsum  = ws + 2458752;                // 8192 fl (doubles as zh over-read slack) -> end 2466944
    u16* gi      = (u16*)(ws + 2466944);        // 12582912 fl -> end 15049856
    u16* ch      = (u16*)(ws + 15049856);       // 4194304 fl -> end 19244160 (~77 MB)

    const int MT = B_ * T_;                     // 32768

    // merged setup: all weight conversions + fold + accum zero (801 blocks)
    setup_conv<<<801, 256, 0, stream>>>(Wh, Wht, Wi, Wit, Wp, Wpt,
                                        W_enc, b_enc, W_proj, b_proj, Wct, bc, accum);
    // zh = bf16(x @ Wct^T + bc)   (M=32768, N=128, K=256; A converted in-reg)
    gemm_mfma_f32a<<<dim3(1, MT / 64), 256, 0, stream>>>(x, Wct, bc, zh, P_, F_);
    // gi = bf16(zh @ Wit^T + bi)  (M=32768, N=768, K=128)
    gemm_mfma<<<dim3(6, MT / 64), 256, 0, stream>>>(zh, Wit, bi, gi, 3 * H_, P_);
    // GRU scan (blocks 0..63) + zsum (64..127) — r2-proven structure
    gru_zsum_kernel<<<GRUB_ + B_, 512, 0, stream>>>(gi, Wht, bhn, ch, zh, zsum);
    // fused loss: r2 skeleton + launch_bounds(512,4) + dbuf Zt (1 barrier/iter)
    loss_fused<<<dim3(4, B_, K_), 512, 0, stream>>>(ch, Wpt, bp, zh, zsum, accum);
    finalize<<<1, 256, 0, stream>>>(accum, out);
}